// Round 7
// baseline (9.775 us; speedup 1.0000x reference)
//
#include <hip/hip_runtime.h>
#include <math.h>

struct ConsTab {
    float cst[64];      // x-half at [0..29], y-half at [32..61]
    float rr[30][6];    // out[t] = cst + sum_r rr[t][r]*b6[r]
};

// ---------------- host-side constant derivation (runs at capture time) -------
static double h_binom(int n, int k) {
    if (k < 0 || k > n) return 0.0;
    double c = 1.0;
    for (int i = 0; i < k; ++i) c = c * (double)(n - i) / (double)(i + 1);
    return c;
}
static double h_bern(int n, int k, double t) {
    if (k < 0 || k > n) return 0.0;
    double tp = 1.0, up = 1.0;
    for (int i = 0; i < k; ++i) tp *= t;
    for (int i = 0; i < n - k; ++i) up *= (1.0 - t);
    return h_binom(n, k) * tp * up;
}

static void compute_tab(ConsTab& tab) {
    double P[30][11], Pd[30][11], Pdd[30][11];
    for (int t = 0; t < 30; ++t) {
        double tv = (double)t / 29.0;
        for (int k = 0; k < 11; ++k) {
            P[t][k]   = h_bern(10, k, tv);
            Pd[t][k]  = 10.0 * (h_bern(9, k - 1, tv) - h_bern(9, k, tv));
            Pdd[t][k] = 90.0 * (h_bern(8, k - 2, tv) - 2.0 * h_bern(8, k - 1, tv) + h_bern(8, k, tv));
        }
    }
    double Aeq[6][11];
    for (int k = 0; k < 11; ++k) {
        Aeq[0][k] = P[0][k];  Aeq[1][k] = Pd[0][k];  Aeq[2][k] = Pdd[0][k];
        Aeq[3][k] = P[29][k]; Aeq[4][k] = Pd[29][k]; Aeq[5][k] = Pdd[29][k];
    }
    double E[11][11], G[11][11], M[11][22];
    for (int j = 0; j < 11; ++j)
        for (int k = 0; k < 11; ++k) {
            double sq = 0, sg = 0, se = 0;
            for (int t = 0; t < 30; ++t) { sq += Pdd[t][j] * Pdd[t][k]; sg += P[t][j] * P[t][k]; }
            for (int r = 0; r < 6; ++r) se += Aeq[r][j] * Aeq[r][k];
            E[j][k] = se; G[j][k] = sg;
            M[j][k] = 10.0 * sq + 4.8 * sg + 10.0 * se;
            M[j][11 + k] = (j == k) ? 1.0 : 0.0;
        }
    // Gauss-Jordan (SPD, no pivoting)
    for (int col = 0; col < 11; ++col) {
        double ip = 1.0 / M[col][col];
        for (int c = 0; c < 22; ++c) M[col][c] *= ip;
        for (int r = 0; r < 11; ++r) {
            if (r == col) continue;
            double f = M[r][col];
            for (int c = 0; c < 22; ++c) M[r][c] -= f * M[col][c];
        }
    }
    double Ci[11][11];
    for (int j = 0; j < 11; ++j)
        for (int k = 0; k < 11; ++k) Ci[j][k] = M[j][11 + k];
    double K[11][11], F[11][11], PC[30][11], cP[11];
    for (int j = 0; j < 11; ++j)
        for (int k = 0; k < 11; ++k) {
            double sk = 0, sf = 0;
            for (int m = 0; m < 11; ++m) {
                sk += (10.0 * E[j][m] - 4.8 * G[j][m]) * Ci[m][k];
                sf += E[j][m] * Ci[m][k];
            }
            K[j][k] = sk; F[j][k] = sf;
        }
    for (int t = 0; t < 30; ++t)
        for (int m = 0; m < 11; ++m) {
            double s = 0;
            for (int j = 0; j < 11; ++j) s += P[t][j] * Ci[j][m];
            PC[t][m] = -s;
        }
    for (int k = 0; k < 11; ++k) {
        double s = 0;
        for (int t = 0; t < 30; ++t) s += P[t][k];
        cP[k] = s;
    }
    // A = [[-K, I], [-10F, I]]; compute (Pr,Sr) = (A^299, sum_{i<299} A^i)
    static thread_local double A[22][22], Pr[22][22], Sr[22][22], T1[22][22], T2[22][22];
    for (int r = 0; r < 22; ++r)
        for (int c = 0; c < 22; ++c) {
            double v;
            if (r < 11) v = (c < 11) ? -K[r][c]           : ((c - 11 == r)      ? 1.0 : 0.0);
            else        v = (c < 11) ? -10.0 * F[r - 11][c] : ((c - 11 == r - 11) ? 1.0 : 0.0);
            A[r][c] = v; Pr[r][c] = v; Sr[r][c] = (r == c) ? 1.0 : 0.0;
        }
    const int bits[8] = {0, 0, 1, 0, 1, 0, 1, 1};   // 299 after MSB
    for (int s = 0; s < 8; ++s) {
        for (int r = 0; r < 22; ++r)
            for (int c = 0; c < 22; ++c) {
                double a1 = 0, a2 = 0;
                for (int k = 0; k < 22; ++k) { a1 += Pr[r][k] * Pr[k][c]; a2 += Pr[r][k] * Sr[k][c]; }
                T1[r][c] = a1; T2[r][c] = a2 + Sr[r][c];
            }
        for (int r = 0; r < 22; ++r)
            for (int c = 0; c < 22; ++c) { Pr[r][c] = T1[r][c]; Sr[r][c] = T2[r][c]; }
        if (bits[s]) {
            for (int r = 0; r < 22; ++r)
                for (int c = 0; c < 22; ++c) {
                    double a1 = 0, a2 = 0;
                    for (int k = 0; k < 22; ++k) { a1 += A[r][k] * Pr[k][c]; a2 += A[r][k] * Sr[k][c]; }
                    T1[r][c] = a1; T2[r][c] = a2 + ((r == c) ? 1.0 : 0.0);
                }
            for (int r = 0; r < 22; ++r)
                for (int c = 0; c < 22; ++c) { Pr[r][c] = T1[r][c]; Sr[r][c] = T2[r][c]; }
        }
    }
    // V = -10 Pr_qq - 20 Sr_qq - 10 Sr_qz ; u = Pr_qq cP ; VA = V Aeq^T
    double V[11][11], u[11], VA[11][6];
    for (int j = 0; j < 11; ++j) {
        for (int k = 0; k < 11; ++k)
            V[j][k] = -10.0 * Pr[j][k] - 20.0 * Sr[j][k] - 10.0 * Sr[j][11 + k];
        double s = 0;
        for (int k = 0; k < 11; ++k) s += Pr[j][k] * cP[k];
        u[j] = s;
    }
    for (int j = 0; j < 11; ++j)
        for (int r = 0; r < 6; ++r) {
            double s = 0;
            for (int k = 0; k < 11; ++k) s += V[j][k] * Aeq[r][k];
            VA[j][r] = s;
        }
    for (int i = 0; i < 64; ++i) tab.cst[i] = 0.f;
    for (int hf = 0; hf < 2; ++hf) {
        double S0 = hf ? -20000.8 : 40004.79;     // sum_o(obs + d0*c0) per half
        for (int t = 0; t < 30; ++t) {
            double s = 0;
            for (int j = 0; j < 11; ++j) s += PC[t][j] * u[j];
            tab.cst[hf * 32 + t] = (float)(-1.2 * S0 * s);
        }
    }
    for (int t = 0; t < 30; ++t)
        for (int r = 0; r < 6; ++r) {
            double s = 0;
            for (int j = 0; j < 11; ++j) s += PC[t][j] * VA[j][r];
            tab.rr[t][r] = (float)s;
        }
}

// ------- fused MLP + affine output: 1 wave per batch, 2 hidden units/lane -----
__global__ __launch_bounds__(64) void fused_kernel(
        const float* __restrict__ x, const float* __restrict__ b,
        const float* __restrict__ W1, const float* __restrict__ b1,
        const float* __restrict__ W2, const float* __restrict__ b2,
        const ConsTab tab, float* __restrict__ out) {
    const int bb = blockIdx.x, j = threadIdx.x;       // j in [0,64)
    float acc0 = b1[j], acc1 = b1[j + 64];
    #pragma unroll
    for (int i = 0; i < 54; ++i) {
        float xv = x[bb * 54 + i];
        acc0 = fmaf(xv, W1[i * 128 + j], acc0);
        acc1 = fmaf(xv, W1[i * 128 + j + 64], acc1);
    }
    float h0 = fmaxf(acc0, 0.0f), h1 = fmaxf(acc1, 0.0f);
    float t3 = fmaf(h1, W2[(j + 64) * 12 + 3], h0 * W2[j * 12 + 3]);
    float t9 = fmaf(h1, W2[(j + 64) * 12 + 9], h0 * W2[j * 12 + 9]);
    #pragma unroll
    for (int m = 32; m >= 1; m >>= 1) { t3 += __shfl_xor(t3, m); t9 += __shfl_xor(t9, m); }
    if (j < 60) {
        float p3 = t3 + b2[3];
        float p9 = t9 + b2[9];
        int hf = (j >= 30) ? 1 : 0;
        int t = j - hf * 30;
        float o = tab.cst[hf * 32 + t];
        float pv = hf ? p9 : p3;   // b_gen[3]/b_gen[9] (MASK==0 entries)
        #pragma unroll
        for (int r = 0; r < 6; ++r) {
            float bv = (r == 3) ? pv : b[bb * 12 + hf * 6 + r];
            o = fmaf(tab.rr[t][r], bv, o);
        }
        out[bb * 60 + j] = o;
    }
}

extern "C" void kernel_launch(void* const* d_in, const int* in_sizes, int n_in,
                              void* d_out, int out_size, void* d_ws, size_t ws_size,
                              hipStream_t stream) {
    const float* x  = (const float*)d_in[0];
    const float* b  = (const float*)d_in[1];
    const float* W1 = (const float*)d_in[2];
    const float* b1 = (const float*)d_in[3];
    const float* W2 = (const float*)d_in[4];
    const float* b2 = (const float*)d_in[5];
    float* out = (float*)d_out;
    int nb = in_sizes[0] / 54;   // 1024

    ConsTab tab;
    compute_tab(tab);            // host, deterministic, capture-time only

    hipLaunchKernelGGL(fused_kernel, dim3(nb), dim3(64), 0, stream,
                       x, b, W1, b1, W2, b2, tab, out);
}